// Round 2
// 105.483 us; speedup vs baseline: 1.0322x; 1.0322x over previous
//
#include <hip/hip_runtime.h>
#include <hip/hip_fp16.h>
#include <math.h>

#define V_ 128
#define K_ 32
#define C_ 256
#define L_ 4
#define N_ 4096
#define F_ 16
#define E_ 8192
#define B_ 512
#define EPS_ 1e-6f

__device__ __forceinline__ __half2 u2h(unsigned u) {
    __half2 h; *reinterpret_cast<unsigned*>(&h) = u; return h;
}
__device__ __forceinline__ unsigned h2u(__half2 h) {
    return *reinterpret_cast<unsigned*>(&h);
}
__device__ __forceinline__ __half b2h(unsigned short u) {
    __half h; *reinterpret_cast<unsigned short*>(&h) = u; return h;
}
__device__ __forceinline__ unsigned short h2b(__half h) {
    return *reinterpret_cast<unsigned short*>(&h);
}
// ROCm has no __hmax2; exact packed max via lossless half->float round-trip.
__device__ __forceinline__ __half2 hmax2(__half2 a, __half2 b) {
    float2 fa = __half22float2(a), fb = __half22float2(b);
    return __floats2half2_rn(fmaxf(fa.x, fb.x), fmaxf(fa.y, fb.y));
}

// ---------------------------------------------------------------------------
// Fused prep kernel (one launch, 1217 blocks x 256 threads):
//  [0,64):      PIW transposed [l][q][n] as uint4, entry = (sc_idx*4) |
//               half_bits(w_f)<<16.  (*4 = pre-shifted LDS byte offset; the
//               transpose makes mega's 4 index-vector loads per node fully
//               coalesced: lane n reads piw4[q*N+n], contiguous 16B/lane.)
//  [64,192):    PP[l][e] = (c0*4) | (c1*4)<<16  (pre-shifted byte offsets)
//  [192,1216):  inv_row[n] = 1/Σ_c(ip[n,c]+EPS)   (4 rows/block)
//  block 1216:  lrpsum = log(Σ_n(rp[n]+EPS))
// ---------------------------------------------------------------------------
__global__ __launch_bounds__(256) void prep_kernel(const float* __restrict__ sp,
                                                   const int* __restrict__ prod,
                                                   const int* __restrict__ sc,
                                                   const float* __restrict__ ip,
                                                   const float* __restrict__ rp,
                                                   unsigned* __restrict__ PIW,
                                                   unsigned* __restrict__ PP,
                                                   float* __restrict__ inv_row,
                                                   float* __restrict__ lrpsum) {
    int blk = blockIdx.x;
    int tid = threadIdx.x;
    if (blk < 64) {
        int idx = blk * 256 + tid;          // (l,n), L*N = 16384
        int l   = idx >> 12;                // N = 4096 = 2^12
        int n   = idx & (N_ - 1);
        const float4* row4 = (const float4*)(sp + (size_t)idx * F_);
        float v[F_];
        float s = 0.f;
#pragma unroll
        for (int q = 0; q < 4; q++) {
            float4 r = row4[q];
            v[4*q+0] = r.x + EPS_; v[4*q+1] = r.y + EPS_;
            v[4*q+2] = r.z + EPS_; v[4*q+3] = r.w + EPS_;
            s += v[4*q+0] + v[4*q+1] + v[4*q+2] + v[4*q+3];
        }
        float inv = 1.f / s;
        const int* scr = sc + (size_t)idx * F_;
        uint4* dst = (uint4*)PIW + ((size_t)l * 4) * N_ + n;
#pragma unroll
        for (int q = 0; q < 4; q++) {
            uint4 o;
            o.x = (unsigned)(unsigned short)(scr[4*q+0] << 2) |
                  ((unsigned)h2b(__float2half(v[4*q+0] * inv)) << 16);
            o.y = (unsigned)(unsigned short)(scr[4*q+1] << 2) |
                  ((unsigned)h2b(__float2half(v[4*q+1] * inv)) << 16);
            o.z = (unsigned)(unsigned short)(scr[4*q+2] << 2) |
                  ((unsigned)h2b(__float2half(v[4*q+2] * inv)) << 16);
            o.w = (unsigned)(unsigned short)(scr[4*q+3] << 2) |
                  ((unsigned)h2b(__float2half(v[4*q+3] * inv)) << 16);
            dst[(size_t)q * N_] = o;
        }
    } else if (blk < 192) {
        int idx = (blk - 64) * 256 + tid;   // (l,e), L*E = 32768
        int2 c  = ((const int2*)prod)[idx];
        PP[idx] = ((unsigned)c.x << 2) | ((unsigned)c.y << 18);  // pre-shifted
    } else if (blk < 192 + 1024) {
        int rblk = blk - 192;
        int n    = rblk * 4 + (tid >> 6);
        int lane = tid & 63;
        const float* row = ip + (size_t)n * C_;
        float t = 0.f;
#pragma unroll
        for (int i = 0; i < 4; i++) t += row[lane + 64 * i] + EPS_;
#pragma unroll
        for (int off = 32; off; off >>= 1) t += __shfl_down(t, off, 64);
        if (lane == 0) inv_row[n] = 1.f / t;
    } else {
        __shared__ float smem[4];
        float acc = 0.f;
        for (int i = tid; i < N_; i += 256) acc += rp[i] + EPS_;
#pragma unroll
        for (int off = 32; off; off >>= 1) acc += __shfl_down(acc, off, 64);
        if ((tid & 63) == 0) smem[tid >> 6] = acc;
        __syncthreads();
        if (tid == 0) lrpsum[0] = __logf(smem[0] + smem[1] + smem[2] + smem[3]);
    }
}

// ---------------------------------------------------------------------------
// Mega kernel: whole circuit per 2-wide b-slice, scaled-linear in LDS.
// R12 refinements over R11 (issue/latency diet; LDS gather count is fixed):
//  - indices pre-shifted to byte offsets in prep -> 1 v_and per gather addr
//  - weight broadcast via v_perm_b32 (1 instr, replaces shr+pack)
//  - PIW transposed [l][q][n] uint4 -> all 4 vector loads per node coalesced
//  - dual 8-deep __hfma2 accumulator chains per node (halved dep latency)
// Grid = B/2 = 256 blocks x 1024 threads; LDS = 32+16 KB.
// ---------------------------------------------------------------------------

// sum-gather step: 1 v_and + 1 ds_read + 1 v_perm + 1 v_pk_fma
#define SSTEP(QQ, ACC) { unsigned q_ = (QQ); \
    (ACC) = __hfma2(u2h(*(const unsigned*)((const char*)em + (q_ & 0xfffcu))), \
                    u2h(__builtin_amdgcn_perm(q_, q_, 0x03020302u)), (ACC)); }

// product step: (nm0*ha)*(nm1*ha), each factor <=1 so no fp16 overflow
#define PSTEP(QQ, DST) { unsigned q_ = (QQ); \
    __half2 t0_ = __hmul2(u2h(*(const unsigned*)((const char*)nm + (q_ & 0xfffcu))), ha); \
    __half2 t1_ = __hmul2(u2h(*(const unsigned*)((const char*)nm + (q_ >> 16))), ha); \
    (DST) = h2u(__hmul2(t0_, t1_)); }

__global__ __launch_bounds__(1024) void mega_kernel(const float* __restrict__ ip,
                                                    const int* __restrict__ inputs,
                                                    const float* __restrict__ inv_row,
                                                    const float* __restrict__ rp,
                                                    const unsigned* __restrict__ PIW,
                                                    const unsigned* __restrict__ PP,
                                                    const float* __restrict__ lrpsum,
                                                    float* __restrict__ out) {
    __shared__ __align__(16) unsigned em[E_];  // half2 (b0,b1) per product (32 KB)
    __shared__ __align__(16) unsigned nm[N_];  // half2 (b0,b1) per sum node (16 KB)
    __shared__ unsigned redm[16];
    __shared__ float    redf[32];
    int tid  = threadIdx.x;
    int lane = tid & 63;
    int w    = tid >> 6;
    int b0   = blockIdx.x * 2, b1 = b0 + 1;

    // ---- input layer: linear u = (ip[n,x]+EPS)/rowsum, renorm by per-b max
    float2 u[4];
    float mx0 = 0.f, mx1 = 0.f;
#pragma unroll
    for (int p = 0; p < 4; p++) {
        int n  = p * 1024 + tid;
        int v  = n >> 5;                       // K = 32
        int x0 = inputs[b0 * V_ + v];
        int x1 = inputs[b1 * V_ + v];
        float invr = inv_row[n];
        u[p].x = (ip[(size_t)n * C_ + x0] + EPS_) * invr;
        u[p].y = (ip[(size_t)n * C_ + x1] + EPS_) * invr;
        mx0 = fmaxf(mx0, u[p].x);
        mx1 = fmaxf(mx1, u[p].y);
    }
#pragma unroll
    for (int off = 32; off; off >>= 1) {
        mx0 = fmaxf(mx0, __shfl_down(mx0, off, 64));
        mx1 = fmaxf(mx1, __shfl_down(mx1, off, 64));
    }
    if (lane == 0) { redf[w] = mx0; redf[16 + w] = mx1; }
    __syncthreads();
    float m0 = redf[0], m1 = redf[16];
#pragma unroll
    for (int i = 1; i < 16; i++) { m0 = fmaxf(m0, redf[i]); m1 = fmaxf(m1, redf[16 + i]); }
    float inv0 = 1.f / m0, inv1 = 1.f / m1;
    float sg0 = __logf(m0), sg1 = __logf(m1);   // true = stored * e^sigma
#pragma unroll
    for (int p = 0; p < 4; p++)
        nm[p * 1024 + tid] = h2u(__floats2half2_rn(u[p].x * inv0, u[p].y * inv1));
    __syncthreads();

    __half2 ha  = __floats2half2_rn(1.f, 1.f);   // deferred scale (this layer)
    float   af0 = 1.f, af1 = 1.f;                // its exact fp32 value

    // ---- layers 0..2: product (scale folded) -> sum (store unscaled) ------
    for (int l = 0; l < L_ - 1; l++) {
        const uint4* pp4 = (const uint4*)(PP + (size_t)l * E_);
#pragma unroll
        for (int p = 0; p < 2; p++) {
            uint4 c = pp4[p * 1024 + tid];
            uint4 o;
            PSTEP(c.x, o.x); PSTEP(c.y, o.y); PSTEP(c.z, o.z); PSTEP(c.w, o.w);
            ((uint4*)em)[p * 1024 + tid] = o;
        }
        sg0 = 2.f * sg0 + 2.f * __logf(af0);   // af applied this layer
        sg1 = 2.f * sg1 + 2.f * __logf(af1);
        __syncthreads();

        const uint4* piw4 = (const uint4*)PIW + (size_t)l * 4 * N_;
        __half2 hm = u2h(0u);
#pragma unroll
        for (int p = 0; p < 4; p++) {
            int n = p * 1024 + tid;
            uint4 q0 = piw4[n];
            uint4 q1 = piw4[N_ + n];
            uint4 q2 = piw4[2 * N_ + n];
            uint4 q3 = piw4[3 * N_ + n];
            __half2 a0 = u2h(0u), a1 = u2h(0u);
            SSTEP(q0.x, a0) SSTEP(q0.y, a1) SSTEP(q0.z, a0) SSTEP(q0.w, a1)
            SSTEP(q1.x, a0) SSTEP(q1.y, a1) SSTEP(q1.z, a0) SSTEP(q1.w, a1)
            SSTEP(q2.x, a0) SSTEP(q2.y, a1) SSTEP(q2.z, a0) SSTEP(q2.w, a1)
            SSTEP(q3.x, a0) SSTEP(q3.y, a1) SSTEP(q3.z, a0) SSTEP(q3.w, a1)
            __half2 acc = __hadd2(a0, a1);
            nm[n] = h2u(acc);              // store unscaled (overlaps reduction)
            hm    = hmax2(hm, acc);
        }
#pragma unroll
        for (int off = 32; off; off >>= 1)
            hm = hmax2(hm, u2h(__shfl_down(h2u(hm), off, 64)));
        if (lane == 0) redm[w] = h2u(hm);
        __syncthreads();                   // redm ready AND nm writes visible
        __half2 M = u2h(redm[0]);
#pragma unroll
        for (int i = 1; i < 16; i++) M = hmax2(M, u2h(redm[i]));
        float M0 = __half2float(__low2half(M)), M1 = __half2float(__high2half(M));
        ha  = __floats2half2_rn(fminf(1.f / M0, 60000.f), fminf(1.f / M1, 60000.f));
        af0 = __half2float(__low2half(ha));
        af1 = __half2float(__high2half(ha));
        sg0 -= 2.f * __logf(af0);          // scale will be applied next product
        sg1 -= 2.f * __logf(af1);
        // net per layer: sigma_new = 2*sigma_old - 2*log(af_applied), exactly once
    }

    // ---- layer 3: product (scale folded) -> sum fused with root dot -------
    {
        const uint4* pp4 = (const uint4*)(PP + (size_t)(L_ - 1) * E_);
#pragma unroll
        for (int p = 0; p < 2; p++) {
            uint4 c = pp4[p * 1024 + tid];
            uint4 o;
            PSTEP(c.x, o.x); PSTEP(c.y, o.y); PSTEP(c.z, o.z); PSTEP(c.w, o.w);
            ((uint4*)em)[p * 1024 + tid] = o;
        }
        sg0 = 2.f * sg0 + 2.f * __logf(af0);
        sg1 = 2.f * sg1 + 2.f * __logf(af1);
        __syncthreads();

        const uint4* piw4 = (const uint4*)PIW + (size_t)(L_ - 1) * 4 * N_;
        float S0 = 0.f, S1 = 0.f;
#pragma unroll
        for (int p = 0; p < 4; p++) {
            int n = p * 1024 + tid;
            uint4 q0 = piw4[n];
            uint4 q1 = piw4[N_ + n];
            uint4 q2 = piw4[2 * N_ + n];
            uint4 q3 = piw4[3 * N_ + n];
            __half2 a0 = u2h(0u), a1 = u2h(0u);
            SSTEP(q0.x, a0) SSTEP(q0.y, a1) SSTEP(q0.z, a0) SSTEP(q0.w, a1)
            SSTEP(q1.x, a0) SSTEP(q1.y, a1) SSTEP(q1.z, a0) SSTEP(q1.w, a1)
            SSTEP(q2.x, a0) SSTEP(q2.y, a1) SSTEP(q2.z, a0) SSTEP(q2.w, a1)
            SSTEP(q3.x, a0) SSTEP(q3.y, a1) SSTEP(q3.z, a0) SSTEP(q3.w, a1)
            float2 vv = __half22float2(__hadd2(a0, a1));
            float  r  = rp[n] + EPS_;
            S0 += r * vv.x;
            S1 += r * vv.y;
        }
#pragma unroll
        for (int off = 32; off; off >>= 1) {
            S0 += __shfl_down(S0, off, 64);
            S1 += __shfl_down(S1, off, 64);
        }
        if (lane == 0) { redf[w] = S0; redf[16 + w] = S1; }
        __syncthreads();
        if (tid == 0) {
            float s0 = 0.f, s1 = 0.f;
#pragma unroll
            for (int i = 0; i < 16; i++) { s0 += redf[i]; s1 += redf[16 + i]; }
            float lr = lrpsum[0];
            out[b0] = __logf(s0) + sg0 - lr;
            out[b1] = __logf(s1) + sg1 - lr;
        }
    }
}

extern "C" void kernel_launch(void* const* d_in, const int* in_sizes, int n_in,
                              void* d_out, int out_size, void* d_ws, size_t ws_size,
                              hipStream_t stream) {
    const int*   inputs = (const int*)d_in[0];     // (B, V) int32
    const int*   prod   = (const int*)d_in[1];     // (L, E, 2) int32
    const int*   sc     = (const int*)d_in[2];     // (L, N, F) int32
    const float* ip     = (const float*)d_in[3];   // (V, K, C) f32
    const float* sp     = (const float*)d_in[4];   // (L, N, F) f32
    const float* rp     = (const float*)d_in[5];   // (N,) f32
    float* out = (float*)d_out;                    // (B,) f32

    unsigned* PIW     = (unsigned*)d_ws;                     // L*4*N uint4 (1 MB)
    unsigned* PP      = PIW + (size_t)L_ * N_ * F_;          // L*E u32 (128 KB)
    float*    inv_row = (float*)(PP + (size_t)L_ * E_);      // N floats
    float*    lrpsum  = inv_row + N_;                        // 1 float

    prep_kernel<<<64 + 128 + 1024 + 1, 256, 0, stream>>>(sp, prod, sc, ip, rp,
                                                         PIW, PP, inv_row, lrpsum);
    mega_kernel<<<B_ / 2, 1024, 0, stream>>>(ip, inputs, inv_row, rp,
                                             PIW, PP, lrpsum, out);
}

// Round 3
// 104.037 us; speedup vs baseline: 1.0465x; 1.0139x over previous
//
#include <hip/hip_runtime.h>
#include <hip/hip_fp16.h>
#include <math.h>

#define V_ 128
#define K_ 32
#define C_ 256
#define L_ 4
#define N_ 4096
#define F_ 16
#define E_ 8192
#define B_ 512
#define EPS_ 1e-6f

__device__ __forceinline__ __half2 u2h(unsigned u) {
    __half2 h; *reinterpret_cast<unsigned*>(&h) = u; return h;
}
__device__ __forceinline__ unsigned h2u(__half2 h) {
    return *reinterpret_cast<unsigned*>(&h);
}
__device__ __forceinline__ __half b2h(unsigned short u) {
    __half h; *reinterpret_cast<unsigned short*>(&h) = u; return h;
}
__device__ __forceinline__ unsigned short h2b(__half h) {
    return *reinterpret_cast<unsigned short*>(&h);
}
// Packed half max in ONE instruction (VOP3P); values are non-negative so
// NaN/signed-zero semantics are irrelevant.
__device__ __forceinline__ __half2 hmax2(__half2 a, __half2 b) {
    unsigned r, ua = h2u(a), ub = h2u(b);
    asm("v_pk_max_f16 %0, %1, %2" : "=v"(r) : "v"(ua), "v"(ub));
    return u2h(r);
}
// LDS-only barrier: drain DS ops, DO NOT drain vmcnt -> prefetched global
// loads stay in flight across the barrier (T4 counted-wait idea; the
// compiler's __syncthreads would emit s_waitcnt vmcnt(0) and kill overlap).
__device__ __forceinline__ void barrier_lds_only() {
    asm volatile("s_waitcnt lgkmcnt(0)" ::: "memory");
    __builtin_amdgcn_s_barrier();
}

// ---------------------------------------------------------------------------
// Fused prep kernel (one launch, 1217 blocks x 256 threads):
//  [0,64):      PIW transposed [l][q][n] as uint4, entry = (sc_idx*4) |
//               half_bits(w_f)<<16   (pre-shifted LDS byte offset; coalesced)
//  [64,192):    PP[l][e] = (c0*4) | (c1*4)<<16  (pre-shifted byte offsets)
//  [192,1216):  inv_row[n] = 1/Σ_c(ip[n,c]+EPS)   (4 rows/block)
//  block 1216:  lrpsum = log(Σ_n(rp[n]+EPS))
// ---------------------------------------------------------------------------
__global__ __launch_bounds__(256) void prep_kernel(const float* __restrict__ sp,
                                                   const int* __restrict__ prod,
                                                   const int* __restrict__ sc,
                                                   const float* __restrict__ ip,
                                                   const float* __restrict__ rp,
                                                   unsigned* __restrict__ PIW,
                                                   unsigned* __restrict__ PP,
                                                   float* __restrict__ inv_row,
                                                   float* __restrict__ lrpsum) {
    int blk = blockIdx.x;
    int tid = threadIdx.x;
    if (blk < 64) {
        int idx = blk * 256 + tid;          // (l,n), L*N = 16384
        int l   = idx >> 12;                // N = 4096 = 2^12
        int n   = idx & (N_ - 1);
        const float4* row4 = (const float4*)(sp + (size_t)idx * F_);
        float v[F_];
        float s = 0.f;
#pragma unroll
        for (int q = 0; q < 4; q++) {
            float4 r = row4[q];
            v[4*q+0] = r.x + EPS_; v[4*q+1] = r.y + EPS_;
            v[4*q+2] = r.z + EPS_; v[4*q+3] = r.w + EPS_;
            s += v[4*q+0] + v[4*q+1] + v[4*q+2] + v[4*q+3];
        }
        float inv = 1.f / s;
        const int* scr = sc + (size_t)idx * F_;
        uint4* dst = (uint4*)PIW + ((size_t)l * 4) * N_ + n;
#pragma unroll
        for (int q = 0; q < 4; q++) {
            uint4 o;
            o.x = (unsigned)(unsigned short)(scr[4*q+0] << 2) |
                  ((unsigned)h2b(__float2half(v[4*q+0] * inv)) << 16);
            o.y = (unsigned)(unsigned short)(scr[4*q+1] << 2) |
                  ((unsigned)h2b(__float2half(v[4*q+1] * inv)) << 16);
            o.z = (unsigned)(unsigned short)(scr[4*q+2] << 2) |
                  ((unsigned)h2b(__float2half(v[4*q+2] * inv)) << 16);
            o.w = (unsigned)(unsigned short)(scr[4*q+3] << 2) |
                  ((unsigned)h2b(__float2half(v[4*q+3] * inv)) << 16);
            dst[(size_t)q * N_] = o;
        }
    } else if (blk < 192) {
        int idx = (blk - 64) * 256 + tid;   // (l,e), L*E = 32768
        int2 c  = ((const int2*)prod)[idx];
        PP[idx] = ((unsigned)c.x << 2) | ((unsigned)c.y << 18);  // pre-shifted
    } else if (blk < 192 + 1024) {
        int rblk = blk - 192;
        int n    = rblk * 4 + (tid >> 6);
        int lane = tid & 63;
        const float* row = ip + (size_t)n * C_;
        float t = 0.f;
#pragma unroll
        for (int i = 0; i < 4; i++) t += row[lane + 64 * i] + EPS_;
#pragma unroll
        for (int off = 32; off; off >>= 1) t += __shfl_down(t, off, 64);
        if (lane == 0) inv_row[n] = 1.f / t;
    } else {
        __shared__ float smem[4];
        float acc = 0.f;
        for (int i = tid; i < N_; i += 256) acc += rp[i] + EPS_;
#pragma unroll
        for (int off = 32; off; off >>= 1) acc += __shfl_down(acc, off, 64);
        if ((tid & 63) == 0) smem[tid >> 6] = acc;
        __syncthreads();
        if (tid == 0) lrpsum[0] = __logf(smem[0] + smem[1] + smem[2] + smem[3]);
    }
}

// ---------------------------------------------------------------------------
// Mega kernel R13 (over R12, which was LDS-issue-bound):
//  - lgkmcnt-only barriers: prefetched global loads survive all 8 in-loop
//    barriers (compiler's __syncthreads drains vmcnt(0) -> serialized loads)
//  - full software pipeline of global streams: PP(l+1) issued during
//    gather(l); PIW q(p=0) issued during product(l); 1-deep q prefetch in
//    the gather loop; rp[] loaded upfront in layer 3
//  - hmax2 = v_pk_max_f16 (1 VALU vs ~6 via float round-trip)
// Grid = B/2 = 256 blocks x 1024 threads; LDS = 32+16 KB.
// ---------------------------------------------------------------------------

// sum-gather step: 1 v_and + 1 ds_read + 1 v_perm + 1 v_pk_fma
#define SSTEP(QQ, ACC) { unsigned q_ = (QQ); \
    (ACC) = __hfma2(u2h(*(const unsigned*)((const char*)em + (q_ & 0xfffcu))), \
                    u2h(__builtin_amdgcn_perm(q_, q_, 0x03020302u)), (ACC)); }

// product step: (nm0*ha)*(nm1*ha), each factor <=1 so no fp16 overflow
#define PSTEP(QQ, DST) { unsigned q_ = (QQ); \
    __half2 t0_ = __hmul2(u2h(*(const unsigned*)((const char*)nm + (q_ & 0xfffcu))), ha); \
    __half2 t1_ = __hmul2(u2h(*(const unsigned*)((const char*)nm + (q_ >> 16))), ha); \
    (DST) = h2u(__hmul2(t0_, t1_)); }

__global__ __launch_bounds__(1024) void mega_kernel(const float* __restrict__ ip,
                                                    const int* __restrict__ inputs,
                                                    const float* __restrict__ inv_row,
                                                    const float* __restrict__ rp,
                                                    const unsigned* __restrict__ PIW,
                                                    const unsigned* __restrict__ PP,
                                                    const float* __restrict__ lrpsum,
                                                    float* __restrict__ out) {
    __shared__ __align__(16) unsigned em[E_];  // half2 (b0,b1) per product (32 KB)
    __shared__ __align__(16) unsigned nm[N_];  // half2 (b0,b1) per sum node (16 KB)
    __shared__ unsigned redm[16];
    __shared__ float    redf[32];
    int tid  = threadIdx.x;
    int lane = tid & 63;
    int w    = tid >> 6;
    int b0   = blockIdx.x * 2, b1 = b0 + 1;

    // ---- input layer: linear u = (ip[n,x]+EPS)/rowsum, renorm by per-b max
    float2 u[4];
    float mx0 = 0.f, mx1 = 0.f;
#pragma unroll
    for (int p = 0; p < 4; p++) {
        int n  = p * 1024 + tid;
        int v  = n >> 5;                       // K = 32
        int x0 = inputs[b0 * V_ + v];
        int x1 = inputs[b1 * V_ + v];
        float invr = inv_row[n];
        u[p].x = (ip[(size_t)n * C_ + x0] + EPS_) * invr;
        u[p].y = (ip[(size_t)n * C_ + x1] + EPS_) * invr;
        mx0 = fmaxf(mx0, u[p].x);
        mx1 = fmaxf(mx1, u[p].y);
    }
#pragma unroll
    for (int off = 32; off; off >>= 1) {
        mx0 = fmaxf(mx0, __shfl_down(mx0, off, 64));
        mx1 = fmaxf(mx1, __shfl_down(mx1, off, 64));
    }
    if (lane == 0) { redf[w] = mx0; redf[16 + w] = mx1; }
    __syncthreads();
    float m0 = redf[0], m1 = redf[16];
#pragma unroll
    for (int i = 1; i < 16; i++) { m0 = fmaxf(m0, redf[i]); m1 = fmaxf(m1, redf[16 + i]); }
    float inv0 = 1.f / m0, inv1 = 1.f / m1;
    float sg0 = __logf(m0), sg1 = __logf(m1);   // true = stored * e^sigma
#pragma unroll
    for (int p = 0; p < 4; p++)
        nm[p * 1024 + tid] = h2u(__floats2half2_rn(u[p].x * inv0, u[p].y * inv1));

    // prefetch layer-0 product children while nm writes drain
    const uint4* pp0 = (const uint4*)PP;
    uint4 cA = pp0[tid], cB = pp0[1024 + tid];
    barrier_lds_only();

    __half2 ha  = __floats2half2_rn(1.f, 1.f);   // deferred scale (this layer)
    float   af0 = 1.f, af1 = 1.f;                // its exact fp32 value

    // ---- layers 0..2: product (scale folded) -> sum (store unscaled) ------
    for (int l = 0; l < L_ - 1; l++) {
        const uint4* piw4 = (const uint4*)PIW + (size_t)l * 4 * N_;
        // issue q(p=0) loads now; consumed after the barrier
        uint4 q0 = piw4[tid];
        uint4 q1 = piw4[N_ + tid];
        uint4 q2 = piw4[2 * N_ + tid];
        uint4 q3 = piw4[3 * N_ + tid];
        {
            uint4 o;
            PSTEP(cA.x, o.x); PSTEP(cA.y, o.y); PSTEP(cA.z, o.z); PSTEP(cA.w, o.w);
            ((uint4*)em)[tid] = o;
            PSTEP(cB.x, o.x); PSTEP(cB.y, o.y); PSTEP(cB.z, o.z); PSTEP(cB.w, o.w);
            ((uint4*)em)[1024 + tid] = o;
        }
        sg0 = 2.f * sg0 + 2.f * __logf(af0);   // af applied this layer
        sg1 = 2.f * sg1 + 2.f * __logf(af1);
        barrier_lds_only();

        const uint4* ppn = (const uint4*)PP + (size_t)(l + 1) * (E_ / 4);
        __half2 hm = u2h(0u);
#pragma unroll
        for (int p = 0; p < 4; p++) {
            int n = p * 1024 + tid;
            uint4 r0 = q0, r1 = q1, r2 = q2, r3 = q3;
            if (p < 3) {
                int nn = n + 1024;
                q0 = piw4[nn]; q1 = piw4[N_ + nn];
                q2 = piw4[2 * N_ + nn]; q3 = piw4[3 * N_ + nn];
            } else {
                cA = ppn[tid]; cB = ppn[1024 + tid];   // next layer's children
            }
            __half2 a0 = u2h(0u), a1 = u2h(0u);
            SSTEP(r0.x, a0) SSTEP(r0.y, a1) SSTEP(r0.z, a0) SSTEP(r0.w, a1)
            SSTEP(r1.x, a0) SSTEP(r1.y, a1) SSTEP(r1.z, a0) SSTEP(r1.w, a1)
            SSTEP(r2.x, a0) SSTEP(r2.y, a1) SSTEP(r2.z, a0) SSTEP(r2.w, a1)
            SSTEP(r3.x, a0) SSTEP(r3.y, a1) SSTEP(r3.z, a0) SSTEP(r3.w, a1)
            __half2 acc = __hadd2(a0, a1);
            nm[n] = h2u(acc);              // store unscaled (overlaps reduction)
            hm    = hmax2(hm, acc);
        }
#pragma unroll
        for (int off = 32; off; off >>= 1)
            hm = hmax2(hm, u2h(__shfl_down(h2u(hm), off, 64)));
        if (lane == 0) redm[w] = h2u(hm);
        barrier_lds_only();                // redm ready AND nm writes visible
        __half2 M = u2h(redm[0]);
#pragma unroll
        for (int i = 1; i < 16; i++) M = hmax2(M, u2h(redm[i]));
        float M0 = __half2float(__low2half(M)), M1 = __half2float(__high2half(M));
        ha  = __floats2half2_rn(fminf(1.f / M0, 60000.f), fminf(1.f / M1, 60000.f));
        af0 = __half2float(__low2half(ha));
        af1 = __half2float(__high2half(ha));
        sg0 -= 2.f * __logf(af0);          // scale will be applied next product
        sg1 -= 2.f * __logf(af1);
        // net per layer: sigma_new = 2*sigma_old - 2*log(af_applied), exactly once
    }

    // ---- layer 3: product (scale folded) -> sum fused with root dot -------
    {
        const uint4* piw4 = (const uint4*)PIW + (size_t)(L_ - 1) * 4 * N_;
        uint4 q0 = piw4[tid];
        uint4 q1 = piw4[N_ + tid];
        uint4 q2 = piw4[2 * N_ + tid];
        uint4 q3 = piw4[3 * N_ + tid];
        float rv0 = rp[tid], rv1 = rp[1024 + tid],
              rv2 = rp[2048 + tid], rv3 = rp[3072 + tid];
        {
            uint4 o;
            PSTEP(cA.x, o.x); PSTEP(cA.y, o.y); PSTEP(cA.z, o.z); PSTEP(cA.w, o.w);
            ((uint4*)em)[tid] = o;
            PSTEP(cB.x, o.x); PSTEP(cB.y, o.y); PSTEP(cB.z, o.z); PSTEP(cB.w, o.w);
            ((uint4*)em)[1024 + tid] = o;
        }
        sg0 = 2.f * sg0 + 2.f * __logf(af0);
        sg1 = 2.f * sg1 + 2.f * __logf(af1);
        barrier_lds_only();

        float S0 = 0.f, S1 = 0.f;
#pragma unroll
        for (int p = 0; p < 4; p++) {
            int n = p * 1024 + tid;
            uint4 r0 = q0, r1 = q1, r2 = q2, r3 = q3;
            if (p < 3) {
                int nn = n + 1024;
                q0 = piw4[nn]; q1 = piw4[N_ + nn];
                q2 = piw4[2 * N_ + nn]; q3 = piw4[3 * N_ + nn];
            }
            __half2 a0 = u2h(0u), a1 = u2h(0u);
            SSTEP(r0.x, a0) SSTEP(r0.y, a1) SSTEP(r0.z, a0) SSTEP(r0.w, a1)
            SSTEP(r1.x, a0) SSTEP(r1.y, a1) SSTEP(r1.z, a0) SSTEP(r1.w, a1)
            SSTEP(r2.x, a0) SSTEP(r2.y, a1) SSTEP(r2.z, a0) SSTEP(r2.w, a1)
            SSTEP(r3.x, a0) SSTEP(r3.y, a1) SSTEP(r3.z, a0) SSTEP(r3.w, a1)
            float2 vv = __half22float2(__hadd2(a0, a1));
            float  r  = (p == 0 ? rv0 : p == 1 ? rv1 : p == 2 ? rv2 : rv3) + EPS_;
            S0 += r * vv.x;
            S1 += r * vv.y;
        }
#pragma unroll
        for (int off = 32; off; off >>= 1) {
            S0 += __shfl_down(S0, off, 64);
            S1 += __shfl_down(S1, off, 64);
        }
        if (lane == 0) { redf[w] = S0; redf[16 + w] = S1; }
        __syncthreads();
        if (tid == 0) {
            float s0 = 0.f, s1 = 0.f;
#pragma unroll
            for (int i = 0; i < 16; i++) { s0 += redf[i]; s1 += redf[16 + i]; }
            float lr = lrpsum[0];
            out[b0] = __logf(s0) + sg0 - lr;
            out[b1] = __logf(s1) + sg1 - lr;
        }
    }
}

extern "C" void kernel_launch(void* const* d_in, const int* in_sizes, int n_in,
                              void* d_out, int out_size, void* d_ws, size_t ws_size,
                              hipStream_t stream) {
    const int*   inputs = (const int*)d_in[0];     // (B, V) int32
    const int*   prod   = (const int*)d_in[1];     // (L, E, 2) int32
    const int*   sc     = (const int*)d_in[2];     // (L, N, F) int32
    const float* ip     = (const float*)d_in[3];   // (V, K, C) f32
    const float* sp     = (const float*)d_in[4];   // (L, N, F) f32
    const float* rp     = (const float*)d_in[5];   // (N,) f32
    float* out = (float*)d_out;                    // (B,) f32

    unsigned* PIW     = (unsigned*)d_ws;                     // L*4*N uint4 (1 MB)
    unsigned* PP      = PIW + (size_t)L_ * N_ * F_;          // L*E u32 (128 KB)
    float*    inv_row = (float*)(PP + (size_t)L_ * E_);      // N floats
    float*    lrpsum  = inv_row + N_;                        // 1 float

    prep_kernel<<<64 + 128 + 1024 + 1, 256, 0, stream>>>(sp, prod, sc, ip, rp,
                                                         PIW, PP, inv_row, lrpsum);
    mega_kernel<<<B_ / 2, 1024, 0, stream>>>(ip, inputs, inv_row, rp,
                                             PIW, PP, lrpsum, out);
}

// Round 4
// 97.329 us; speedup vs baseline: 1.1187x; 1.0689x over previous
//
#include <hip/hip_runtime.h>
#include <hip/hip_fp16.h>
#include <math.h>

#define V_ 128
#define K_ 32
#define C_ 256
#define L_ 4
#define N_ 4096
#define F_ 16
#define E_ 8192
#define B_ 512
#define EPS_ 1e-6f

__device__ __forceinline__ __half2 u2h(unsigned u) {
    __half2 h; *reinterpret_cast<unsigned*>(&h) = u; return h;
}
__device__ __forceinline__ unsigned h2u(__half2 h) {
    return *reinterpret_cast<unsigned*>(&h);
}
__device__ __forceinline__ __half b2h(unsigned short u) {
    __half h; *reinterpret_cast<unsigned short*>(&h) = u; return h;
}
__device__ __forceinline__ unsigned short h2b(__half h) {
    return *reinterpret_cast<unsigned short*>(&h);
}
// Packed half max in ONE instruction (VOP3P); values are non-negative so
// NaN/signed-zero semantics are irrelevant.
__device__ __forceinline__ __half2 hmax2(__half2 a, __half2 b) {
    unsigned r, ua = h2u(a), ub = h2u(b);
    asm("v_pk_max_f16 %0, %1, %2" : "=v"(r) : "v"(ua), "v"(ub));
    return u2h(r);
}
// LDS-only barrier: drain DS ops, DO NOT drain vmcnt -> prefetched global
// loads stay in flight across the barrier (T4 counted-wait idea; the
// compiler's __syncthreads would emit s_waitcnt vmcnt(0) and kill overlap).
__device__ __forceinline__ void barrier_lds_only() {
    asm volatile("s_waitcnt lgkmcnt(0)" ::: "memory");
    __builtin_amdgcn_s_barrier();
}

// ---------------------------------------------------------------------------
// Fused prep kernel (one launch, 321 blocks x 256 threads):
//  [0,64):      PIW transposed [l][q][n] as uint4, entry = (sc_idx*4) |
//               half_bits(w_f)<<16   (pre-shifted LDS byte offset; coalesced)
//  [64,192):    PP[l][e] = (c0*4) | (c1*4)<<16  (pre-shifted byte offsets)
//  [192,320):   ipT[v][c][k] = (ip[v*32+k][c]+EPS) * 1/Σ_c(ip[v*32+k][c]+EPS)
//               -> mega's input layer becomes fully coalesced (lanes share
//               (v,x), read consecutive k) with EPS+invr pre-folded.  Row
//               sums computed in-block from the LDS tile (inv_row pass and
//               its global round-trip eliminated).
//  block 320:   lrpsum = log(Σ_n(rp[n]+EPS))
// ---------------------------------------------------------------------------
__global__ __launch_bounds__(256) void prep_kernel(const float* __restrict__ sp,
                                                   const int* __restrict__ prod,
                                                   const int* __restrict__ sc,
                                                   const float* __restrict__ ip,
                                                   const float* __restrict__ rp,
                                                   unsigned* __restrict__ PIW,
                                                   unsigned* __restrict__ PP,
                                                   float* __restrict__ ipT,
                                                   float* __restrict__ lrpsum) {
    int blk = blockIdx.x;
    int tid = threadIdx.x;
    if (blk < 64) {
        int idx = blk * 256 + tid;          // (l,n), L*N = 16384
        int l   = idx >> 12;                // N = 4096 = 2^12
        int n   = idx & (N_ - 1);
        const float4* row4 = (const float4*)(sp + (size_t)idx * F_);
        float v[F_];
        float s = 0.f;
#pragma unroll
        for (int q = 0; q < 4; q++) {
            float4 r = row4[q];
            v[4*q+0] = r.x + EPS_; v[4*q+1] = r.y + EPS_;
            v[4*q+2] = r.z + EPS_; v[4*q+3] = r.w + EPS_;
            s += v[4*q+0] + v[4*q+1] + v[4*q+2] + v[4*q+3];
        }
        float inv = 1.f / s;
        const int* scr = sc + (size_t)idx * F_;
        uint4* dst = (uint4*)PIW + ((size_t)l * 4) * N_ + n;
#pragma unroll
        for (int q = 0; q < 4; q++) {
            uint4 o;
            o.x = (unsigned)(unsigned short)(scr[4*q+0] << 2) |
                  ((unsigned)h2b(__float2half(v[4*q+0] * inv)) << 16);
            o.y = (unsigned)(unsigned short)(scr[4*q+1] << 2) |
                  ((unsigned)h2b(__float2half(v[4*q+1] * inv)) << 16);
            o.z = (unsigned)(unsigned short)(scr[4*q+2] << 2) |
                  ((unsigned)h2b(__float2half(v[4*q+2] * inv)) << 16);
            o.w = (unsigned)(unsigned short)(scr[4*q+3] << 2) |
                  ((unsigned)h2b(__float2half(v[4*q+3] * inv)) << 16);
            dst[(size_t)q * N_] = o;
        }
    } else if (blk < 192) {
        int idx = (blk - 64) * 256 + tid;   // (l,e), L*E = 32768
        int2 c  = ((const int2*)prod)[idx];
        PP[idx] = ((unsigned)c.x << 2) | ((unsigned)c.y << 18);  // pre-shifted
    } else if (blk < 320) {
        // ---- transpose+normalize one v-group (32 rows x 256 cols) --------
        int v = blk - 192;                  // 0..127
        __shared__ float T[32][257];        // +1 pad: conflict-free both axes
        __shared__ float P[256];
        __shared__ float invr_s[32];
        const float* src = ip + (size_t)v * (K_ * C_);
        // coalesced row loads; EPS folded at load
#pragma unroll 4
        for (int k = 0; k < 32; k++)
            T[k][tid] = src[k * C_ + tid] + EPS_;
        __syncthreads();
        {   // partial row sums: lane k of each 32-lane group sums one c-chunk
            int k = tid & 31, j = tid >> 5;
            float s = 0.f;
#pragma unroll
            for (int i = 0; i < 32; i++) s += T[k][j * 32 + i];
            P[tid] = s;
        }
        __syncthreads();
        if (tid < 32) {
            float s = 0.f;
#pragma unroll
            for (int j = 0; j < 8; j++) s += P[j * 32 + tid];
            invr_s[tid] = 1.f / s;
        }
        __syncthreads();
        // write ipT[v][c][k], coalesced in k (lanes 0..31 = k), invr folded
        float* dstv = ipT + (size_t)v * (C_ * K_);
        int k = tid & 31, cg = tid >> 5;
        float invk = invr_s[k];
#pragma unroll 4
        for (int jj = 0; jj < 32; jj++) {
            int c = jj * 8 + cg;
            dstv[c * K_ + k] = T[k][c] * invk;
        }
    } else {
        __shared__ float smem[4];
        float acc = 0.f;
        for (int i = tid; i < N_; i += 256) acc += rp[i] + EPS_;
#pragma unroll
        for (int off = 32; off; off >>= 1) acc += __shfl_down(acc, off, 64);
        if ((tid & 63) == 0) smem[tid >> 6] = acc;
        __syncthreads();
        if (tid == 0) lrpsum[0] = __logf(smem[0] + smem[1] + smem[2] + smem[3]);
    }
}

// ---------------------------------------------------------------------------
// Mega kernel R14 (over R13):
//  - input layer reads pre-normalized TRANSPOSED ipT: lanes sharing (v,x)
//    read 32 consecutive k -> 128B-coalesced wave loads (was: 64 scattered
//    cache lines per wave-instr), EPS+invr pre-folded, inv_row loads gone
//  - everything else: R13 pipeline (lgkmcnt-only barriers, PP/PIW/rp
//    prefetch streams, v_pk_max_f16)
// Grid = B/2 = 256 blocks x 1024 threads; LDS = 32+16 KB.
// ---------------------------------------------------------------------------

// sum-gather step: 1 v_and + 1 ds_read + 1 v_perm + 1 v_pk_fma
#define SSTEP(QQ, ACC) { unsigned q_ = (QQ); \
    (ACC) = __hfma2(u2h(*(const unsigned*)((const char*)em + (q_ & 0xfffcu))), \
                    u2h(__builtin_amdgcn_perm(q_, q_, 0x03020302u)), (ACC)); }

// product step: (nm0*ha)*(nm1*ha), each factor <=1 so no fp16 overflow
#define PSTEP(QQ, DST) { unsigned q_ = (QQ); \
    __half2 t0_ = __hmul2(u2h(*(const unsigned*)((const char*)nm + (q_ & 0xfffcu))), ha); \
    __half2 t1_ = __hmul2(u2h(*(const unsigned*)((const char*)nm + (q_ >> 16))), ha); \
    (DST) = h2u(__hmul2(t0_, t1_)); }

__global__ __launch_bounds__(1024) void mega_kernel(const float* __restrict__ ipT,
                                                    const int* __restrict__ inputs,
                                                    const float* __restrict__ rp,
                                                    const unsigned* __restrict__ PIW,
                                                    const unsigned* __restrict__ PP,
                                                    const float* __restrict__ lrpsum,
                                                    float* __restrict__ out) {
    __shared__ __align__(16) unsigned em[E_];  // half2 (b0,b1) per product (32 KB)
    __shared__ __align__(16) unsigned nm[N_];  // half2 (b0,b1) per sum node (16 KB)
    __shared__ unsigned redm[16];
    __shared__ float    redf[32];
    int tid  = threadIdx.x;
    int lane = tid & 63;
    int w    = tid >> 6;
    int b0   = blockIdx.x * 2, b1 = b0 + 1;

    // ---- input layer: u = ipT[v][x][k]  (pre-normalized), renorm by max --
    float2 u[4];
    float mx0 = 0.f, mx1 = 0.f;
#pragma unroll
    for (int p = 0; p < 4; p++) {
        int n = p * 1024 + tid;
        int v = n >> 5, k = n & 31;            // K = 32
        int x0 = inputs[b0 * V_ + v];
        int x1 = inputs[b1 * V_ + v];
        u[p].x = ipT[(((size_t)v << 8) + x0) * K_ + k];
        u[p].y = ipT[(((size_t)v << 8) + x1) * K_ + k];
        mx0 = fmaxf(mx0, u[p].x);
        mx1 = fmaxf(mx1, u[p].y);
    }
#pragma unroll
    for (int off = 32; off; off >>= 1) {
        mx0 = fmaxf(mx0, __shfl_down(mx0, off, 64));
        mx1 = fmaxf(mx1, __shfl_down(mx1, off, 64));
    }
    if (lane == 0) { redf[w] = mx0; redf[16 + w] = mx1; }
    __syncthreads();
    float m0 = redf[0], m1 = redf[16];
#pragma unroll
    for (int i = 1; i < 16; i++) { m0 = fmaxf(m0, redf[i]); m1 = fmaxf(m1, redf[16 + i]); }
    float inv0 = 1.f / m0, inv1 = 1.f / m1;
    float sg0 = __logf(m0), sg1 = __logf(m1);   // true = stored * e^sigma
#pragma unroll
    for (int p = 0; p < 4; p++)
        nm[p * 1024 + tid] = h2u(__floats2half2_rn(u[p].x * inv0, u[p].y * inv1));

    // prefetch layer-0 product children while nm writes drain
    const uint4* pp0 = (const uint4*)PP;
    uint4 cA = pp0[tid], cB = pp0[1024 + tid];
    barrier_lds_only();

    __half2 ha  = __floats2half2_rn(1.f, 1.f);   // deferred scale (this layer)
    float   af0 = 1.f, af1 = 1.f;                // its exact fp32 value

    // ---- layers 0..2: product (scale folded) -> sum (store unscaled) ------
    for (int l = 0; l < L_ - 1; l++) {
        const uint4* piw4 = (const uint4*)PIW + (size_t)l * 4 * N_;
        // issue q(p=0) loads now; consumed after the barrier
        uint4 q0 = piw4[tid];
        uint4 q1 = piw4[N_ + tid];
        uint4 q2 = piw4[2 * N_ + tid];
        uint4 q3 = piw4[3 * N_ + tid];
        {
            uint4 o;
            PSTEP(cA.x, o.x); PSTEP(cA.y, o.y); PSTEP(cA.z, o.z); PSTEP(cA.w, o.w);
            ((uint4*)em)[tid] = o;
            PSTEP(cB.x, o.x); PSTEP(cB.y, o.y); PSTEP(cB.z, o.z); PSTEP(cB.w, o.w);
            ((uint4*)em)[1024 + tid] = o;
        }
        sg0 = 2.f * sg0 + 2.f * __logf(af0);   // af applied this layer
        sg1 = 2.f * sg1 + 2.f * __logf(af1);
        barrier_lds_only();

        const uint4* ppn = (const uint4*)PP + (size_t)(l + 1) * (E_ / 4);
        __half2 hm = u2h(0u);
#pragma unroll
        for (int p = 0; p < 4; p++) {
            int n = p * 1024 + tid;
            uint4 r0 = q0, r1 = q1, r2 = q2, r3 = q3;
            if (p < 3) {
                int nn = n + 1024;
                q0 = piw4[nn]; q1 = piw4[N_ + nn];
                q2 = piw4[2 * N_ + nn]; q3 = piw4[3 * N_ + nn];
            } else {
                cA = ppn[tid]; cB = ppn[1024 + tid];   // next layer's children
            }
            __half2 a0 = u2h(0u), a1 = u2h(0u);
            SSTEP(r0.x, a0) SSTEP(r0.y, a1) SSTEP(r0.z, a0) SSTEP(r0.w, a1)
            SSTEP(r1.x, a0) SSTEP(r1.y, a1) SSTEP(r1.z, a0) SSTEP(r1.w, a1)
            SSTEP(r2.x, a0) SSTEP(r2.y, a1) SSTEP(r2.z, a0) SSTEP(r2.w, a1)
            SSTEP(r3.x, a0) SSTEP(r3.y, a1) SSTEP(r3.z, a0) SSTEP(r3.w, a1)
            __half2 acc = __hadd2(a0, a1);
            nm[n] = h2u(acc);              // store unscaled (overlaps reduction)
            hm    = hmax2(hm, acc);
        }
#pragma unroll
        for (int off = 32; off; off >>= 1)
            hm = hmax2(hm, u2h(__shfl_down(h2u(hm), off, 64)));
        if (lane == 0) redm[w] = h2u(hm);
        barrier_lds_only();                // redm ready AND nm writes visible
        __half2 M = u2h(redm[0]);
#pragma unroll
        for (int i = 1; i < 16; i++) M = hmax2(M, u2h(redm[i]));
        float M0 = __half2float(__low2half(M)), M1 = __half2float(__high2half(M));
        ha  = __floats2half2_rn(fminf(1.f / M0, 60000.f), fminf(1.f / M1, 60000.f));
        af0 = __half2float(__low2half(ha));
        af1 = __half2float(__high2half(ha));
        sg0 -= 2.f * __logf(af0);          // scale will be applied next product
        sg1 -= 2.f * __logf(af1);
        // net per layer: sigma_new = 2*sigma_old - 2*log(af_applied), exactly once
    }

    // ---- layer 3: product (scale folded) -> sum fused with root dot -------
    {
        const uint4* piw4 = (const uint4*)PIW + (size_t)(L_ - 1) * 4 * N_;
        uint4 q0 = piw4[tid];
        uint4 q1 = piw4[N_ + tid];
        uint4 q2 = piw4[2 * N_ + tid];
        uint4 q3 = piw4[3 * N_ + tid];
        float rv0 = rp[tid], rv1 = rp[1024 + tid],
              rv2 = rp[2048 + tid], rv3 = rp[3072 + tid];
        {
            uint4 o;
            PSTEP(cA.x, o.x); PSTEP(cA.y, o.y); PSTEP(cA.z, o.z); PSTEP(cA.w, o.w);
            ((uint4*)em)[tid] = o;
            PSTEP(cB.x, o.x); PSTEP(cB.y, o.y); PSTEP(cB.z, o.z); PSTEP(cB.w, o.w);
            ((uint4*)em)[1024 + tid] = o;
        }
        sg0 = 2.f * sg0 + 2.f * __logf(af0);
        sg1 = 2.f * sg1 + 2.f * __logf(af1);
        barrier_lds_only();

        float S0 = 0.f, S1 = 0.f;
#pragma unroll
        for (int p = 0; p < 4; p++) {
            int n = p * 1024 + tid;
            uint4 r0 = q0, r1 = q1, r2 = q2, r3 = q3;
            if (p < 3) {
                int nn = n + 1024;
                q0 = piw4[nn]; q1 = piw4[N_ + nn];
                q2 = piw4[2 * N_ + nn]; q3 = piw4[3 * N_ + nn];
            }
            __half2 a0 = u2h(0u), a1 = u2h(0u);
            SSTEP(r0.x, a0) SSTEP(r0.y, a1) SSTEP(r0.z, a0) SSTEP(r0.w, a1)
            SSTEP(r1.x, a0) SSTEP(r1.y, a1) SSTEP(r1.z, a0) SSTEP(r1.w, a1)
            SSTEP(r2.x, a0) SSTEP(r2.y, a1) SSTEP(r2.z, a0) SSTEP(r2.w, a1)
            SSTEP(r3.x, a0) SSTEP(r3.y, a1) SSTEP(r3.z, a0) SSTEP(r3.w, a1)
            float2 vv = __half22float2(__hadd2(a0, a1));
            float  r  = (p == 0 ? rv0 : p == 1 ? rv1 : p == 2 ? rv2 : rv3) + EPS_;
            S0 += r * vv.x;
            S1 += r * vv.y;
        }
#pragma unroll
        for (int off = 32; off; off >>= 1) {
            S0 += __shfl_down(S0, off, 64);
            S1 += __shfl_down(S1, off, 64);
        }
        if (lane == 0) { redf[w] = S0; redf[16 + w] = S1; }
        __syncthreads();
        if (tid == 0) {
            float s0 = 0.f, s1 = 0.f;
#pragma unroll
            for (int i = 0; i < 16; i++) { s0 += redf[i]; s1 += redf[16 + i]; }
            float lr = lrpsum[0];
            out[b0] = __logf(s0) + sg0 - lr;
            out[b1] = __logf(s1) + sg1 - lr;
        }
    }
}

extern "C" void kernel_launch(void* const* d_in, const int* in_sizes, int n_in,
                              void* d_out, int out_size, void* d_ws, size_t ws_size,
                              hipStream_t stream) {
    const int*   inputs = (const int*)d_in[0];     // (B, V) int32
    const int*   prod   = (const int*)d_in[1];     // (L, E, 2) int32
    const int*   sc     = (const int*)d_in[2];     // (L, N, F) int32
    const float* ip     = (const float*)d_in[3];   // (V, K, C) f32
    const float* sp     = (const float*)d_in[4];   // (L, N, F) f32
    const float* rp     = (const float*)d_in[5];   // (N,) f32
    float* out = (float*)d_out;                    // (B,) f32

    float*    ipT     = (float*)d_ws;                        // V*C*K f32 (4 MB)
    unsigned* PIW     = (unsigned*)(ipT + (size_t)V_ * C_ * K_);  // L*4*N uint4 (1 MB)
    unsigned* PP      = PIW + (size_t)L_ * N_ * F_;          // L*E u32 (128 KB)
    float*    lrpsum  = (float*)(PP + (size_t)L_ * E_);      // 1 float

    prep_kernel<<<64 + 128 + 128 + 1, 256, 0, stream>>>(sp, prod, sc, ip, rp,
                                                        PIW, PP, ipT, lrpsum);
    mega_kernel<<<B_ / 2, 1024, 0, stream>>>(ipT, inputs, rp,
                                             PIW, PP, lrpsum, out);
}